// Round 4
// baseline (1125.132 us; speedup 1.0000x reference)
//
#include <hip/hip_runtime.h>
#include <stdint.h>

// ---------------------------------------------------------------------------
// scores[b,s] = v . tanh( hidden[b] @ Wh + bias + enc[s,b] @ We )
// out[b,s]   = softmax_s(scores)
// Big GEMM: enc_flat[M=65536,K=1024] @ We[K=1024,N=512], bf16 MFMA.
// R6: occupancy + vmcnt-ordering fix.
//   - R5 post-mortem: acc[4][8]=128 AGPR + 128 VGPR = 256 regs -> 2 waves/
//     SIMD, barrier-locked -> zero TLP; and issueA(T+3) preceded loadB(T+2)
//     so L2-fast B waits retired HBM-slow A first (in-order vmcnt).
//   - Now 512 threads / 8 waves (2M x 4N), per-wave 32x128 -> acc[2][8]=64
//     regs; __launch_bounds__(512,4) caps at 128 -> 4 waves/SIMD, 2 indep
//     blocks/CU. Phase order: compute -> writeA -> loadB(T+2) -> issueA(T+3)
//     (sched_barrier-pinned) so B is older than next A.
//   - Keeps: packed fragment-order B (R5), XOR-swizzled bf16 A LDS (R4,
//     conflicts=0), raw lgkm-only barriers (R4).
// ---------------------------------------------------------------------------

typedef float  floatx4 __attribute__((ext_vector_type(4)));
typedef __bf16 bf16x4  __attribute__((ext_vector_type(4)));
typedef __bf16 bf16x8  __attribute__((ext_vector_type(8)));
typedef short  short8  __attribute__((ext_vector_type(8)));

union bfu  { bf16x8 v; short8 s; };
union bfu4 { bf16x4 v; uint2 u; };

#define LOG2E_X2 2.8853900817779268f

// raw barrier: wait own LDS ops only; global prefetches ride across.
#define BAR()                                              \
  do {                                                     \
    asm volatile("s_waitcnt lgkmcnt(0)" ::: "memory");     \
    __builtin_amdgcn_sched_barrier(0);                     \
    __builtin_amdgcn_s_barrier();                          \
    __builtin_amdgcn_sched_barrier(0);                     \
  } while (0)

#define SB() __builtin_amdgcn_sched_barrier(0)

// ---- kernel 0: W[512:1536,:] -> fragment-packed bf16 B.
// Bp element ((T*4+wc)*8+ct)*512 + (q*16+t)*8 + j  <-  W[512 + k][n]
//   where T=k>>5, q=(k>>3)&3, j=k&7, wc=n>>7, ct=(n>>4)&7, t=n&15.
__global__ void wt_convert(const float* __restrict__ W, __bf16* __restrict__ Bp) {
  __shared__ float tile[64][65];                 // +1 pad: conflict-free both ways
  const int kt = blockIdx.x >> 3;                // 16 k-tiles (64 k each)
  const int nt = blockIdx.x & 7;                 // 8 n-tiles (64 n each)
  const int c  = threadIdx.x & 63;
  const int r4 = threadIdx.x >> 6;               // 4 rows per pass
  #pragma unroll 4
  for (int i = 0; i < 16; i++) {
    int r = i * 4 + r4;                          // k-local
    tile[r][c] = W[(long)(512 + kt * 64 + r) * 512 + nt * 64 + c];
  }
  __syncthreads();
  // pack: 8 consecutive k -> one 16B chunk per thread
  const int n_loc = threadIdx.x & 63;
  const int kc4   = threadIdx.x >> 6;            // 0..3
  const int n_g   = nt * 64 + n_loc;
  const int wc    = n_g >> 7;
  const int ct    = (n_g >> 4) & 7;
  const int t     = n_g & 15;
  #pragma unroll
  for (int i = 0; i < 2; i++) {
    int chunk = i * 4 + kc4;                     // k_loc = chunk*8 + j
    int k_g   = kt * 64 + chunk * 8;
    int T     = k_g >> 5;
    int q     = (k_g >> 3) & 3;
    union bfu u;
    #pragma unroll
    for (int j = 0; j < 8; j++) u.v[j] = (__bf16)tile[chunk * 8 + j][n_loc];
    long cidx = ((long)(T * 4 + wc) * 8 + ct) * 64 + q * 16 + t;
    *(bf16x8*)(Bp + cidx * 8) = u.v;
  }
}

// ---- kernel 1: hproj[b][n] = bias[n] + sum_k hidden[b,k] * W[k,n]  (k<512)
__global__ void hproj_kernel(const float* __restrict__ hidden,
                             const float* __restrict__ W,
                             const float* __restrict__ bias,
                             float* __restrict__ hproj) {
  const int tid = threadIdx.x;            // n
  const int b_  = blockIdx.x >> 2;
  const int kc  = blockIdx.x & 3;
  __shared__ float hid[128];
  if (tid < 128) hid[tid] = hidden[b_ * 512 + kc * 128 + tid];
  __syncthreads();
  float acc = (kc == 0) ? bias[tid] : 0.f;
  const float* Wp = W + (long)(kc * 128) * 512 + tid;
  #pragma unroll 8
  for (int k = 0; k < 128; k++) acc = fmaf(hid[k], Wp[(long)k * 512], acc);
  atomicAdd(&hproj[b_ * 512 + tid], acc);
}

// ---- kernel 2: the big GEMM + tanh/v-dot epilogue, 8-wave reg-staged
__global__ __launch_bounds__(512, 4) void gemm_score(
    const float* __restrict__ enc,    // [65536][1024] fp32
    const __bf16* __restrict__ Bp,    // packed B, 1 MB
    const float* __restrict__ hproj,  // [64][512]
    const float* __restrict__ v,      // [512]
    float* __restrict__ scores)       // [64][1024]  ([b][s])
{
  // bf16 A tile, double buffered. elem (c,m,j), c=k/8 in 0..3, m row, j=k%8:
  //   elem addr = c*512 + (m*8 ^ c*16) + j      (XOR = bank swizzle)
  __shared__ __bf16 ldsA[2][2048];
  __shared__ float bscore[64];

  const int tid  = threadIdx.x;
  const int lane = tid & 63;
  const int wv   = tid >> 6;      // 8 waves
  const int wc   = wv & 3;        // n-range [wc*128, wc*128+128)
  const int wr   = wv >> 2;       // m-range [wr*32, wr*32+32)
  const int q    = lane >> 4;
  const int t    = lane & 15;
  const long m0  = (long)blockIdx.x * 64;

  // staging coords: thread -> row m = tid>>3, k-quad kq = tid&7; 16B/thread
  const int m  = tid >> 3;
  const int kq = tid & 7;
  const float* ap = enc + (m0 + m) * 1024 + kq * 4;
  const int c_  = kq >> 1;
  const int jh  = (kq & 1) * 4;
  __bf16* aw0 = &ldsA[0][c_ * 512 + ((m * 8) ^ (c_ * 16)) + jh]; // ds_write_b64
  __bf16* aw1 = &ldsA[1][c_ * 512 + ((m * 8) ^ (c_ * 16)) + jh];

  // fragment read base: lane (q,t), rt -> A[wr*32 + rt*16 + t][q*8..q*8+7]
  const __bf16* ar0 = &ldsA[0][q * 512 + (((wr * 32 + t) * 8) ^ (q * 16))];
  const __bf16* ar1 = &ldsA[1][q * 512 + (((wr * 32 + t) * 8) ^ (q * 16))];

  // packed-B per-lane base: frag(T,ct) at + T*16384 + ct*512 elems
  const __bf16* bpb = Bp + ((long)wc * 512 + lane) * 8;

  if (tid < 64) bscore[tid] = 0.f;

  floatx4 acc[2][8];
  #pragma unroll
  for (int i = 0; i < 2; i++)
    #pragma unroll
    for (int j = 0; j < 8; j++)
      acc[i][j] = (floatx4){0.f, 0.f, 0.f, 0.f};

  floatx4 ra0, ra1, ra2;   // A staging regs: 3 k-steps in flight, 4 regs each
  short8  bfr[2][8];       // B fragments, double buffered

  auto writeA = [&](const floatx4& r, __bf16* dst) {  // cvt once + 8B ds_write
    union bfu4 u;
    #pragma unroll
    for (int j = 0; j < 4; j++) u.v[j] = (__bf16)r[j];
    *(bf16x4*)dst = u.v;
  };
  auto loadB = [&](int T, int s) {           // 8 coalesced 1KB wave-loads
    #pragma unroll
    for (int ct = 0; ct < 8; ct++) {
      union bfu u;
      u.v = *(const bf16x8*)(bpb + (long)T * 16384 + ct * 512);
      bfr[s][ct] = u.s;
    }
  };
  auto compute = [&](const __bf16* base, int bs) {
    #pragma unroll
    for (int rt = 0; rt < 2; rt++) {
      union bfu u;
      u.v = *(const bf16x8*)(base + rt * 128);   // 1 ds_read_b128 per rt
      #pragma unroll
      for (int ct = 0; ct < 8; ct++)
        acc[rt][ct] = __builtin_amdgcn_mfma_f32_16x16x32_bf16(
            u.s, bfr[bs][ct], acc[rt][ct], 0, 0, 0);
    }
  };

  // prologue: A0..A2 in flight, B0/B1 in flight, stage A0 into buf0
  ra0 = *(const floatx4*)(ap);
  ra1 = *(const floatx4*)(ap + 32);
  ra2 = *(const floatx4*)(ap + 64);
  loadB(0, 0);  loadB(1, 1);
  writeA(ra0, aw0);             // compiler waits vmcnt for A0 only
  BAR();

  // Phase T: compute A(T) from buf(T&1) with B(T)=bfr[T&1];
  //   then cvt+write A(T+1) (issued end of T-2; its vmcnt wait sits AFTER
  //   the MFMA issue); then loadB(T+2) (into the set compute just freed);
  //   then issueA(T+3) LAST -> B stays older than the next HBM A load, so
  //   compute's B wait never chains behind an A fetch (in-order vmcnt).
#define PHASE(T, RI, RW)                                   \
  {                                                        \
    compute(((T) & 1) ? ar1 : ar0, (T) & 1);               \
    SB();                                                  \
    if ((T) < 31) writeA(RW, ((T) & 1) ? aw0 : aw1);       \
    if ((T) < 30) loadB((T) + 2, (T) & 1);                 \
    SB();                                                  \
    if ((T) < 29) RI = *(const floatx4*)(ap + ((T) + 3) * 32); \
    BAR();                                                 \
  }

  PHASE(0, ra0, ra1)  PHASE(1, ra1, ra2)  PHASE(2, ra2, ra0)  PHASE(3, ra0, ra1)
  PHASE(4, ra1, ra2)  PHASE(5, ra2, ra0)  PHASE(6, ra0, ra1)  PHASE(7, ra1, ra2)
  PHASE(8, ra2, ra0)  PHASE(9, ra0, ra1)  PHASE(10, ra1, ra2) PHASE(11, ra2, ra0)
  PHASE(12, ra0, ra1) PHASE(13, ra1, ra2) PHASE(14, ra2, ra0) PHASE(15, ra0, ra1)
  PHASE(16, ra1, ra2) PHASE(17, ra2, ra0) PHASE(18, ra0, ra1) PHASE(19, ra1, ra2)
  PHASE(20, ra2, ra0) PHASE(21, ra0, ra1) PHASE(22, ra1, ra2) PHASE(23, ra2, ra0)
  PHASE(24, ra0, ra1) PHASE(25, ra1, ra2) PHASE(26, ra2, ra0) PHASE(27, ra0, ra1)
  PHASE(28, ra1, ra2) PHASE(29, ra2, ra0) PHASE(30, ra0, ra1) PHASE(31, ra1, ra2)
#undef PHASE

  // ---- epilogue: score[row] = sum_n v[n] * tanh(acc + hproj[row][n])
  float vv[8];
  #pragma unroll
  for (int ct = 0; ct < 8; ct++) vv[ct] = v[wc * 128 + ct * 16 + t];

  #pragma unroll
  for (int rt = 0; rt < 2; rt++) {
    #pragma unroll
    for (int r = 0; r < 4; r++) {
      int row = wr * 32 + rt * 16 + q * 4 + r;    // C/D: row=(lane>>4)*4+reg
      const float* hrow = hproj + row * 512 + wc * 128 + t;
      float s = 0.f;
      #pragma unroll
      for (int ct = 0; ct < 8; ct++) {
        float e  = acc[rt][ct][r] + hrow[ct * 16];
        float ex = __builtin_amdgcn_exp2f(e * LOG2E_X2);        // e^(2x)
        float th = 1.f - 2.f * __builtin_amdgcn_rcpf(ex + 1.f); // tanh(x)
        s = fmaf(vv[ct], th, s);
      }
      s += __shfl_xor(s, 1);
      s += __shfl_xor(s, 2);
      s += __shfl_xor(s, 4);
      s += __shfl_xor(s, 8);
      if (t == 0) atomicAdd(&bscore[row], s);
    }
  }
  __syncthreads();   // full sync fine here (once, end of kernel)
  if (tid < 64) scores[(long)tid * 1024 + blockIdx.x] = bscore[tid];
}

// ---- kernel 3: softmax over s for each b
__global__ void softmax_kernel(const float* __restrict__ scores,
                               float* __restrict__ out) {
  const int b_   = blockIdx.x;
  const int tid  = threadIdx.x;
  const int lane = tid & 63;
  const int wv   = tid >> 6;
  __shared__ float redmax[4], redsum[4];

  float x[4];
  #pragma unroll
  for (int i = 0; i < 4; i++) x[i] = scores[b_ * 1024 + i * 256 + tid];
  float mx = fmaxf(fmaxf(x[0], x[1]), fmaxf(x[2], x[3]));
  #pragma unroll
  for (int off = 1; off < 64; off <<= 1) mx = fmaxf(mx, __shfl_xor(mx, off));
  if (lane == 0) redmax[wv] = mx;
  __syncthreads();
  mx = fmaxf(fmaxf(redmax[0], redmax[1]), fmaxf(redmax[2], redmax[3]));

  float e[4], s = 0.f;
  #pragma unroll
  for (int i = 0; i < 4; i++) { e[i] = __expf(x[i] - mx); s += e[i]; }
  #pragma unroll
  for (int off = 1; off < 64; off <<= 1) s += __shfl_xor(s, off);
  if (lane == 0) redsum[wv] = s;
  __syncthreads();
  s = redsum[0] + redsum[1] + redsum[2] + redsum[3];
  float inv = 1.f / s;
  #pragma unroll
  for (int i = 0; i < 4; i++) out[b_ * 1024 + i * 256 + tid] = e[i] * inv;
}

extern "C" void kernel_launch(void* const* d_in, const int* in_sizes, int n_in,
                              void* d_out, int out_size, void* d_ws, size_t ws_size,
                              hipStream_t stream) {
  (void)in_sizes; (void)n_in; (void)out_size; (void)ws_size;
  const float* hidden = (const float*)d_in[0];   // [64,512]
  const float* enc    = (const float*)d_in[1];   // [1024,64,1024]
  const float* W      = (const float*)d_in[2];   // [1536,512]
  const float* bias   = (const float*)d_in[3];   // [512]
  const float* v      = (const float*)d_in[4];   // [512]
  float* out = (float*)d_out;                    // [64,1024]

  char* ws = (char*)d_ws;
  __bf16* Bp    = (__bf16*)ws;                            // 1 MB (packed B)
  float*  hproj = (float*)(ws + (1 << 20));               // 128 KB
  float*  scores= (float*)(ws + (1 << 20) + (128 << 10)); // 256 KB

  hipMemsetAsync(hproj, 0, 64 * 512 * sizeof(float), stream);
  wt_convert<<<128, 256, 0, stream>>>(W, Bp);
  hproj_kernel<<<256, 512, 0, stream>>>(hidden, W, bias, hproj);
  gemm_score<<<1024, 512, 0, stream>>>(enc, Bp, hproj, v, scores);
  softmax_kernel<<<64, 256, 0, stream>>>(scores, out);
}

// Round 6
// 430.161 us; speedup vs baseline: 2.6156x; 2.6156x over previous
//
#include <hip/hip_runtime.h>
#include <stdint.h>

// ---------------------------------------------------------------------------
// scores[b,s] = v . tanh( hidden[b] @ Wh + bias + enc[s,b] @ We )
// out[b,s]   = softmax_s(scores)
// Big GEMM: enc_flat[M=65536,K=1024] @ We[K=1024,N=512], bf16 MFMA.
// R7b: identical to R7 (round-5 bench died on container acquire, not on the
//     kernel; audit found no deadlock/OOB/spill). Theory unchanged:
//     wall = per-CU L1-return bytes on B. Mblock 64 -> 128 (grid 512,
//     1 block/CU resident, 2 generations) -> B bytes/CU halved.
//     8 waves (2M x 4N), per-wave 64x128: acc[4][8]=128 + bfr[2][8] in
//     the proven no-spill budget under __launch_bounds__(512,2).
//     Keeps: packed fragment-order B (R5), XOR-swizzled bf16 A LDS (R4,
//     conflicts=0), raw lgkm-only barriers (R4), R6 issue order
//     (compute -> writeA -> loadB(T+2) -> issueA(T+3)).
// ---------------------------------------------------------------------------

typedef float  floatx4 __attribute__((ext_vector_type(4)));
typedef __bf16 bf16x8  __attribute__((ext_vector_type(8)));
typedef short  short8  __attribute__((ext_vector_type(8)));

union bfu  { bf16x8 v; short8 s; };

#define LOG2E_X2 2.8853900817779268f

// raw barrier: wait own LDS ops only; global prefetches ride across.
#define BAR()                                              \
  do {                                                     \
    asm volatile("s_waitcnt lgkmcnt(0)" ::: "memory");     \
    __builtin_amdgcn_sched_barrier(0);                     \
    __builtin_amdgcn_s_barrier();                          \
    __builtin_amdgcn_sched_barrier(0);                     \
  } while (0)

#define SB() __builtin_amdgcn_sched_barrier(0)

// ---- kernel 0: W[512:1536,:] -> fragment-packed bf16 B.
// Bp frag(T,wc,ct) base elem = ((T*4+wc)*8+ct)*512; lane (q*16+t) holds 8 k.
__global__ void wt_convert(const float* __restrict__ W, __bf16* __restrict__ Bp) {
  __shared__ float tile[64][65];                 // +1 pad: conflict-free both ways
  const int kt = blockIdx.x >> 3;                // 16 k-tiles (64 k each)
  const int nt = blockIdx.x & 7;                 // 8 n-tiles (64 n each)
  const int c  = threadIdx.x & 63;
  const int r4 = threadIdx.x >> 6;               // 4 rows per pass
  #pragma unroll 4
  for (int i = 0; i < 16; i++) {
    int r = i * 4 + r4;                          // k-local
    tile[r][c] = W[(long)(512 + kt * 64 + r) * 512 + nt * 64 + c];
  }
  __syncthreads();
  // pack: 8 consecutive k -> one 16B chunk per thread
  const int n_loc = threadIdx.x & 63;
  const int kc4   = threadIdx.x >> 6;            // 0..3
  const int n_g   = nt * 64 + n_loc;
  const int wc    = n_g >> 7;
  const int ct    = (n_g >> 4) & 7;
  const int t     = n_g & 15;
  #pragma unroll
  for (int i = 0; i < 2; i++) {
    int chunk = i * 4 + kc4;                     // k_loc = chunk*8 + j
    int k_g   = kt * 64 + chunk * 8;
    int T     = k_g >> 5;
    int q     = (k_g >> 3) & 3;
    union bfu u;
    #pragma unroll
    for (int j = 0; j < 8; j++) u.v[j] = (__bf16)tile[chunk * 8 + j][n_loc];
    long cidx = ((long)(T * 4 + wc) * 8 + ct) * 64 + q * 16 + t;
    *(bf16x8*)(Bp + cidx * 8) = u.v;
  }
}

// ---- kernel 1: hproj[b][n] = bias[n] + sum_k hidden[b,k] * W[k,n]  (k<512)
__global__ void hproj_kernel(const float* __restrict__ hidden,
                             const float* __restrict__ W,
                             const float* __restrict__ bias,
                             float* __restrict__ hproj) {
  const int tid = threadIdx.x;            // n
  const int b_  = blockIdx.x >> 2;
  const int kc  = blockIdx.x & 3;
  __shared__ float hid[128];
  if (tid < 128) hid[tid] = hidden[b_ * 512 + kc * 128 + tid];
  __syncthreads();
  float acc = (kc == 0) ? bias[tid] : 0.f;
  const float* Wp = W + (long)(kc * 128) * 512 + tid;
  #pragma unroll 8
  for (int k = 0; k < 128; k++) acc = fmaf(hid[k], Wp[(long)k * 512], acc);
  atomicAdd(&hproj[b_ * 512 + tid], acc);
}

// ---- kernel 2: the big GEMM + tanh/v-dot epilogue, 8-wave 128x512 tile
__global__ __launch_bounds__(512, 2) void gemm_score(
    const float* __restrict__ enc,    // [65536][1024] fp32
    const __bf16* __restrict__ Bp,    // packed B, 1 MB
    const float* __restrict__ hproj,  // [64][512]
    const float* __restrict__ v,      // [512]
    float* __restrict__ scores)       // [64][1024]  ([b][s])
{
  // bf16 A tile 128m x 32k, double buffered (8KB each).
  //   elem addr = c*1024 + (m*8 ^ c*16) + j   (c=k/8 in 0..3, j=k%8)
  __shared__ __bf16 ldsA[2][4096];
  __shared__ float bscore[128];

  const int tid  = threadIdx.x;
  const int lane = tid & 63;
  const int wv   = tid >> 6;      // 8 waves
  const int wc   = wv & 3;        // n-range [wc*128, wc*128+128)
  const int wr   = wv >> 2;       // m-range [wr*64, wr*64+64)
  const int q    = lane >> 4;
  const int t    = lane & 15;
  const long m0  = (long)blockIdx.x * 128;

  // staging coords: thread -> row sm = tid>>2, k-chunk sf = tid&3; 32B/thread
  const int sm = tid >> 2;                       // 0..127
  const int sf = tid & 3;
  const float* ap = enc + (m0 + sm) * 1024 + sf * 8;
  __bf16* aw0 = &ldsA[0][sf * 1024 + ((sm * 8) ^ (sf * 16))];  // ds_write_b128
  __bf16* aw1 = &ldsA[1][sf * 1024 + ((sm * 8) ^ (sf * 16))];

  // fragment read base: lane (q,t), rt -> A[wr*64 + rt*16 + t][q*8..q*8+7]
  // addr = q*1024 + wr*512 + rt*128 + ((t*8)^(q*16))
  const __bf16* ar0 = &ldsA[0][q * 1024 + wr * 512 + ((t * 8) ^ (q * 16))];
  const __bf16* ar1 = &ldsA[1][q * 1024 + wr * 512 + ((t * 8) ^ (q * 16))];

  // packed-B per-lane base: frag(T,ct) at + T*16384 + ct*512 elems
  const __bf16* bpb = Bp + (long)wc * 4096 + (long)lane * 8;

  if (tid < 128) bscore[tid] = 0.f;

  floatx4 acc[4][8];
  #pragma unroll
  for (int i = 0; i < 4; i++)
    #pragma unroll
    for (int j = 0; j < 8; j++)
      acc[i][j] = (floatx4){0.f, 0.f, 0.f, 0.f};

  floatx4 ra[3][2];    // A staging regs: 3 k-steps in flight, 32B each
  short8  bfr[2][8];   // B fragments, double buffered

  auto issueA = [&](int T, int s) {          // global fp32 -> regs (no wait)
    const float* p = ap + T * 32;
    ra[s][0] = *(const floatx4*)(p);
    ra[s][1] = *(const floatx4*)(p + 4);
  };
  auto writeA = [&](int s, __bf16* dst) {    // cvt once + 16B ds_write
    union bfu u;
    #pragma unroll
    for (int j = 0; j < 4; j++) {
      u.v[j]     = (__bf16)ra[s][0][j];
      u.v[4 + j] = (__bf16)ra[s][1][j];
    }
    *(bf16x8*)dst = u.v;
  };
  auto loadB = [&](int T, int s) {           // 8 coalesced 1KB wave-loads
    #pragma unroll
    for (int ct = 0; ct < 8; ct++) {
      union bfu u;
      u.v = *(const bf16x8*)(bpb + (long)T * 16384 + ct * 512);
      bfr[s][ct] = u.s;
    }
  };
  auto compute = [&](const __bf16* base, int bs) {
    #pragma unroll
    for (int rt = 0; rt < 4; rt++) {
      union bfu u;
      u.v = *(const bf16x8*)(base + rt * 128);   // 1 ds_read_b128 per rt
      #pragma unroll
      for (int ct = 0; ct < 8; ct++)
        acc[rt][ct] = __builtin_amdgcn_mfma_f32_16x16x32_bf16(
            u.s, bfr[bs][ct], acc[rt][ct], 0, 0, 0);
    }
  };

  // prologue: A0..A2 in flight, B0/B1 in flight, stage A0 into buf0
  issueA(0, 0); issueA(1, 1); issueA(2, 2);
  loadB(0, 0);  loadB(1, 1);
  writeA(0, aw0);               // compiler waits vmcnt for A0 only
  BAR();

  // Phase T: compute A(T) from buf(T&1) with B(T)=bfr[T&1];
  //   then writeA(T+1) (loaded end of T-2; vmcnt wait covered);
  //   then loadB(T+2); issueA(T+3) LAST so B stays older than the next
  //   HBM A load (in-order vmcnt). Raw barrier: lgkm only.
  //   A(T) lives in ra set T%3: writeA uses (T+1)%3, issueA refills T%3.
#define PHASE(T)                                           \
  {                                                        \
    compute(((T) & 1) ? ar1 : ar0, (T) & 1);               \
    SB();                                                  \
    if ((T) < 31) writeA(((T) + 1) % 3, ((T) & 1) ? aw0 : aw1); \
    if ((T) < 30) loadB((T) + 2, (T) & 1);                 \
    SB();                                                  \
    if ((T) < 29) issueA((T) + 3, (T) % 3);                \
    BAR();                                                 \
  }

  PHASE(0)  PHASE(1)  PHASE(2)  PHASE(3)
  PHASE(4)  PHASE(5)  PHASE(6)  PHASE(7)
  PHASE(8)  PHASE(9)  PHASE(10) PHASE(11)
  PHASE(12) PHASE(13) PHASE(14) PHASE(15)
  PHASE(16) PHASE(17) PHASE(18) PHASE(19)
  PHASE(20) PHASE(21) PHASE(22) PHASE(23)
  PHASE(24) PHASE(25) PHASE(26) PHASE(27)
  PHASE(28) PHASE(29) PHASE(30) PHASE(31)
#undef PHASE

  // ---- epilogue: score[row] = sum_n v[n] * tanh(acc + hproj[b][n])
  // block rows 0..127 -> global m = m0+row = s*64+b: b = row&63,
  // s = blk*2 + (row>>6).
  float vv[8];
  #pragma unroll
  for (int ct = 0; ct < 8; ct++) vv[ct] = v[wc * 128 + ct * 16 + t];

  #pragma unroll
  for (int rt = 0; rt < 4; rt++) {
    #pragma unroll
    for (int r = 0; r < 4; r++) {
      int row = wr * 64 + rt * 16 + q * 4 + r;    // 0..127
      const float* hrow = hproj + (row & 63) * 512 + wc * 128 + t;
      float s = 0.f;
      #pragma unroll
      for (int ct = 0; ct < 8; ct++) {
        float e  = acc[rt][ct][r] + hrow[ct * 16];
        float ex = __builtin_amdgcn_exp2f(e * LOG2E_X2);        // e^(2x)
        float th = 1.f - 2.f * __builtin_amdgcn_rcpf(ex + 1.f); // tanh(x)
        s = fmaf(vv[ct], th, s);
      }
      s += __shfl_xor(s, 1);
      s += __shfl_xor(s, 2);
      s += __shfl_xor(s, 4);
      s += __shfl_xor(s, 8);
      if (t == 0) atomicAdd(&bscore[row], s);
    }
  }
  __syncthreads();   // full sync fine here (once, end of kernel)
  if (tid < 128)
    scores[(long)(tid & 63) * 1024 + blockIdx.x * 2 + (tid >> 6)] = bscore[tid];
}

// ---- kernel 3: softmax over s for each b
__global__ void softmax_kernel(const float* __restrict__ scores,
                               float* __restrict__ out) {
  const int b_   = blockIdx.x;
  const int tid  = threadIdx.x;
  const int lane = tid & 63;
  const int wv   = tid >> 6;
  __shared__ float redmax[4], redsum[4];

  float x[4];
  #pragma unroll
  for (int i = 0; i < 4; i++) x[i] = scores[b_ * 1024 + i * 256 + tid];
  float mx = fmaxf(fmaxf(x[0], x[1]), fmaxf(x[2], x[3]));
  #pragma unroll
  for (int off = 1; off < 64; off <<= 1) mx = fmaxf(mx, __shfl_xor(mx, off));
  if (lane == 0) redmax[wv] = mx;
  __syncthreads();
  mx = fmaxf(fmaxf(redmax[0], redmax[1]), fmaxf(redmax[2], redmax[3]));

  float e[4], s = 0.f;
  #pragma unroll
  for (int i = 0; i < 4; i++) { e[i] = __expf(x[i] - mx); s += e[i]; }
  #pragma unroll
  for (int off = 1; off < 64; off <<= 1) s += __shfl_xor(s, off);
  if (lane == 0) redsum[wv] = s;
  __syncthreads();
  s = redsum[0] + redsum[1] + redsum[2] + redsum[3];
  float inv = 1.f / s;
  #pragma unroll
  for (int i = 0; i < 4; i++) out[b_ * 1024 + i * 256 + tid] = e[i] * inv;
}

extern "C" void kernel_launch(void* const* d_in, const int* in_sizes, int n_in,
                              void* d_out, int out_size, void* d_ws, size_t ws_size,
                              hipStream_t stream) {
  (void)in_sizes; (void)n_in; (void)out_size; (void)ws_size;
  const float* hidden = (const float*)d_in[0];   // [64,512]
  const float* enc    = (const float*)d_in[1];   // [1024,64,1024]
  const float* W      = (const float*)d_in[2];   // [1536,512]
  const float* bias   = (const float*)d_in[3];   // [512]
  const float* v      = (const float*)d_in[4];   // [512]
  float* out = (float*)d_out;                    // [64,1024]

  char* ws = (char*)d_ws;
  __bf16* Bp    = (__bf16*)ws;                            // 1 MB (packed B)
  float*  hproj = (float*)(ws + (1 << 20));               // 128 KB
  float*  scores= (float*)(ws + (1 << 20) + (128 << 10)); // 256 KB

  hipMemsetAsync(hproj, 0, 64 * 512 * sizeof(float), stream);
  wt_convert<<<128, 256, 0, stream>>>(W, Bp);
  hproj_kernel<<<256, 512, 0, stream>>>(hidden, W, bias, hproj);
  gemm_score<<<512, 512, 0, stream>>>(enc, Bp, hproj, v, scores);
  softmax_kernel<<<64, 256, 0, stream>>>(scores, out);
}